// Round 16
// baseline (177.731 us; speedup 1.0000x reference)
//
#include <hip/hip_runtime.h>
#include <math.h>

#define H_ 192
#define W_ 384
#define HW_ 73728

// ---------------------------------------------------------------------------
// K0: fold BN constants once.  prep layout (floats):
// [0..17] s1, [18..35] t1, [36..51] s2, [52..67] t2, [68..83] s3, [84..99] t3
// ---------------------------------------------------------------------------
__global__ void k_prep(
    const float* __restrict__ bn1g, const float* __restrict__ bn1b,
    const float* __restrict__ bn1m, const float* __restrict__ bn1v,
    const float* __restrict__ bn2g, const float* __restrict__ bn2b,
    const float* __restrict__ bn2m, const float* __restrict__ bn2v,
    const float* __restrict__ bn3g, const float* __restrict__ bn3b,
    const float* __restrict__ bn3m, const float* __restrict__ bn3v,
    float* __restrict__ prep)
{
    int t = threadIdx.x;
    if (t < 18) {
        float sc = bn1g[t] * rsqrtf(bn1v[t] + 1e-5f);
        prep[t] = sc; prep[18 + t] = bn1b[t] - bn1m[t] * sc;
    } else if (t >= 32 && t < 48) {
        int c = t - 32;
        float sc = bn2g[c] * rsqrtf(bn2v[c] + 1e-5f);
        prep[36 + c] = sc; prep[52 + c] = bn2b[c] - bn2m[c] * sc;
    } else if (t >= 64 && t < 80) {
        int c = t - 64;
        float sc = bn3g[c] * rsqrtf(bn3v[c] + 1e-5f);
        prep[68 + c] = sc; prep[84 + c] = bn3b[c] - bn3m[c] * sc;
    }
}

// ---------------------------------------------------------------------------
// K1: all projections (unchanged from R15). grid (288,4), 2 px/thread.
// x1/x2/gg stored PIXEL-MAJOR [n][HW][16]; x3 channel-major.
// blockIdx.y: 0 = q+k, 1 = v[0:32], 2 = v[32:64], 3 = gg (single pass).
// ---------------------------------------------------------------------------
__global__ __launch_bounds__(256) void k_projall(
    const float* __restrict__ x, const float* __restrict__ g,
    const float* __restrict__ wq, const float* __restrict__ bq,
    const float* __restrict__ wk, const float* __restrict__ bk,
    const float* __restrict__ wv, const float* __restrict__ bv,
    const float* __restrict__ wg, const float* __restrict__ bg,
    float* __restrict__ x1, float* __restrict__ x2, float* __restrict__ x3,
    float* __restrict__ gg)
{
    int slab = blockIdx.y;
    int tid = blockIdx.x * 256 + threadIdx.x;   // 0..73727
    int n  = tid / (HW_ / 2);
    int s2 = (tid - n * (HW_ / 2)) * 2;

    if (slab == 0) {
        float2 aq[16], ak[16];
#pragma unroll
        for (int o = 0; o < 16; o++) {
            float b0 = bq[o], b1 = bk[o];
            aq[o] = make_float2(b0, b0); ak[o] = make_float2(b1, b1);
        }
        const float* xp = x + n * (64 * HW_) + s2;
#pragma unroll 1
        for (int c0 = 0; c0 < 64; c0 += 4) {
            float2 v[4];
#pragma unroll
            for (int j = 0; j < 4; j++) v[j] = *(const float2*)(xp + (c0 + j) * HW_);
#pragma unroll
            for (int j = 0; j < 4; j++) {
#pragma unroll
                for (int o = 0; o < 16; o++) {
                    float w0 = wq[o * 64 + c0 + j];
                    float w1 = wk[o * 64 + c0 + j];
                    aq[o].x = fmaf(w0, v[j].x, aq[o].x);
                    aq[o].y = fmaf(w0, v[j].y, aq[o].y);
                    ak[o].x = fmaf(w1, v[j].x, ak[o].x);
                    ak[o].y = fmaf(w1, v[j].y, ak[o].y);
                }
            }
        }
        float* d1 = x1 + (n * HW_ + s2) * 16;
        float* d2 = x2 + (n * HW_ + s2) * 16;
#pragma unroll
        for (int o4 = 0; o4 < 4; o4++) {
            *(float4*)(d1 + o4 * 4) =
                make_float4(aq[4*o4].x, aq[4*o4+1].x, aq[4*o4+2].x, aq[4*o4+3].x);
            *(float4*)(d1 + 16 + o4 * 4) =
                make_float4(aq[4*o4].y, aq[4*o4+1].y, aq[4*o4+2].y, aq[4*o4+3].y);
            *(float4*)(d2 + o4 * 4) =
                make_float4(ak[4*o4].x, ak[4*o4+1].x, ak[4*o4+2].x, ak[4*o4+3].x);
            *(float4*)(d2 + 16 + o4 * 4) =
                make_float4(ak[4*o4].y, ak[4*o4+1].y, ak[4*o4+2].y, ak[4*o4+3].y);
        }
    } else if (slab <= 2) {
        int q = slab - 1;
        const float* wsel = wv + q * 2048;
        const float* bsel = bv + q * 32;
        float2 av[32];
#pragma unroll
        for (int o = 0; o < 32; o++) { float b = bsel[o]; av[o] = make_float2(b, b); }
        const float* xp = x + n * (64 * HW_) + s2;
#pragma unroll 1
        for (int c0 = 0; c0 < 64; c0 += 4) {
            float2 v[4];
#pragma unroll
            for (int j = 0; j < 4; j++) v[j] = *(const float2*)(xp + (c0 + j) * HW_);
#pragma unroll
            for (int j = 0; j < 4; j++) {
#pragma unroll
                for (int o = 0; o < 32; o++) {
                    float w = wsel[o * 64 + c0 + j];
                    av[o].x = fmaf(w, v[j].x, av[o].x);
                    av[o].y = fmaf(w, v[j].y, av[o].y);
                }
            }
        }
        float* dst = x3 + (n * 64 + q * 32) * HW_ + s2;
#pragma unroll
        for (int o = 0; o < 32; o++) *(float2*)(dst + o * HW_) = av[o];
    } else {
        float2 a[16];
#pragma unroll
        for (int o = 0; o < 16; o++) { float b = bg[o]; a[o] = make_float2(b, b); }
        const float* gp = g + n * (128 * HW_) + s2;
#pragma unroll 1
        for (int c0 = 0; c0 < 128; c0 += 8) {
            float2 v[8];
#pragma unroll
            for (int j = 0; j < 8; j++) v[j] = *(const float2*)(gp + (c0 + j) * HW_);
#pragma unroll
            for (int j = 0; j < 8; j++) {
#pragma unroll
                for (int o = 0; o < 16; o++) {
                    float w = wg[o * 128 + c0 + j];
                    a[o].x = fmaf(w, v[j].x, a[o].x);
                    a[o].y = fmaf(w, v[j].y, a[o].y);
                }
            }
        }
        float* dst = gg + (n * HW_ + s2) * 16;
#pragma unroll
        for (int o4 = 0; o4 < 4; o4++) {
            *(float4*)(dst + o4 * 4) =
                make_float4(a[4*o4].x, a[4*o4+1].x, a[4*o4+2].x, a[4*o4+3].x);
            *(float4*)(dst + 16 + o4 * 4) =
                make_float4(a[4*o4].y, a[4*o4+1].y, a[4*o4+2].y, a[4*o4+3].y);
        }
    }
}

// ---------------------------------------------------------------------------
// K2: weight logits, ROW-parallel: one thread = one pixel x one kernel-row
// (3 taps). grid (576, 3). Center x1/gg loaded ONCE per 3 taps; the 3
// same-row neighbors are adjacent 64B blocks. Logits stored immediately
// (no persistent tap arrays -> bounded registers). ZERO LDS.
// ---------------------------------------------------------------------------
struct WParams {
    const float *x1, *x2, *gg;
    const float *wp;
    const float *w1a, *w1b, *b1b, *w2a, *b2a;
    const float *prep;
    float *w1o, *w2o;   // [n][9][HW] raw logits
};

__global__ __launch_bounds__(256) void k_wtap3(WParams P)
{
    const float* pr = P.prep;

    int ki = blockIdx.y;          // kernel row 0..2, uniform
    int p = blockIdx.x * 256 + threadIdx.x;
    int n = p / HW_, s = p - n * HW_;
    int hi = s / W_, wi = s - hi * W_;

    int hn = hi + ki - 1; hn = (hn < 0) ? -hn : ((hn >= H_) ? 2 * (H_ - 1) - hn : hn);
    float dlh = (float)(hi - hn) * (2.0f / (H_ - 1));
    const float c_w = 2.0f / (W_ - 1);

    int wn0 = (wi == 0) ? 1 : wi - 1;
    int wn2 = (wi == W_ - 1) ? W_ - 2 : wi + 1;
    int wnj[3] = { wn0, wi, wn2 };
    float dlwj[3] = { (float)(wi - wn0) * c_w, 0.0f, (float)(wi - wn2) * c_w };

    int cenb = (n * HW_ + s) * 16;
    int rowb = (n * HW_ + hn * W_) * 16;

    // ---- center vectors (loaded once for all 3 taps) ----
    float4 A0[4], G0[4];
#pragma unroll
    for (int i = 0; i < 4; i++) A0[i] = *(const float4*)(P.x1 + cenb + i * 4);
#pragma unroll
    for (int i = 0; i < 4; i++) G0[i] = *(const float4*)(P.gg + cenb + i * 4);

    float b1c = P.b1b[0], b2c = P.b2a[0];

    // ---- phase A: w1 logits for the 3 taps ----
#pragma unroll
    for (int j = 0; j < 3; j++) {
        const float* x2p = P.x2 + rowb + wnj[j] * 16;
        float4 A1[4];
#pragma unroll
        for (int i = 0; i < 4; i++) A1[i] = *(const float4*)(x2p + i * 4);

        float f[16];
#pragma unroll
        for (int i = 0; i < 4; i++) {
            f[4*i+0] = fmaxf(fmaf(A0[i].x - A1[i].x, pr[4*i+0], pr[18+4*i+0]), 0.0f);
            f[4*i+1] = fmaxf(fmaf(A0[i].y - A1[i].y, pr[4*i+1], pr[18+4*i+1]), 0.0f);
            f[4*i+2] = fmaxf(fmaf(A0[i].z - A1[i].z, pr[4*i+2], pr[18+4*i+2]), 0.0f);
            f[4*i+3] = fmaxf(fmaf(A0[i].w - A1[i].w, pr[4*i+3], pr[18+4*i+3]), 0.0f);
        }

        float h1[16];
#pragma unroll
        for (int o = 0; o < 16; o++) h1[o] = 0.0f;
#pragma unroll
        for (int c = 0; c < 16; c++) {
#pragma unroll
            for (int o = 0; o < 16; o++) h1[o] = fmaf(P.w1a[o * 18 + c], f[c], h1[o]);
        }
#pragma unroll
        for (int pc = 0; pc < 2; pc++) {
            float ff = fmaxf(fmaf(P.wp[pc * 2 + 0] * dlwj[j] + P.wp[pc * 2 + 1] * dlh,
                                  pr[16 + pc], pr[34 + pc]), 0.0f);
#pragma unroll
            for (int o = 0; o < 16; o++) h1[o] = fmaf(P.w1a[o * 18 + 16 + pc], ff, h1[o]);
        }
        float l1 = b1c;
#pragma unroll
        for (int o = 0; o < 16; o++)
            l1 = fmaf(P.w1b[o], fmaxf(fmaf(h1[o], pr[36 + o], pr[52 + o]), 0.0f), l1);

        P.w1o[(n * 9 + ki * 3 + j) * HW_ + s] = l1;
    }

    // ---- phase B: w2 logits for the 3 taps ----
#pragma unroll
    for (int j = 0; j < 3; j++) {
        const float* ggn = P.gg + rowb + wnj[j] * 16;
        float4 G1[4];
#pragma unroll
        for (int i = 0; i < 4; i++) G1[i] = *(const float4*)(ggn + i * 4);

        float l2 = b2c;
#pragma unroll
        for (int i = 0; i < 4; i++) {
            l2 = fmaf(P.w2a[4*i+0], fmaxf(fmaf(G0[i].x - G1[i].x, pr[68+4*i+0], pr[84+4*i+0]), 0.0f), l2);
            l2 = fmaf(P.w2a[4*i+1], fmaxf(fmaf(G0[i].y - G1[i].y, pr[68+4*i+1], pr[84+4*i+1]), 0.0f), l2);
            l2 = fmaf(P.w2a[4*i+2], fmaxf(fmaf(G0[i].z - G1[i].z, pr[68+4*i+2], pr[84+4*i+2]), 0.0f), l2);
            l2 = fmaf(P.w2a[4*i+3], fmaxf(fmaf(G0[i].w - G1[i].w, pr[68+4*i+3], pr[84+4*i+3]), 0.0f), l2);
        }

        P.w2o[(n * 9 + ki * 3 + j) * HW_ + s] = l2;
    }
}

// ---------------------------------------------------------------------------
// K3: pixel-vectorized 9-tap aggregation + in-register softmax.
// grid (144, 8): 8-channel slabs.
// ---------------------------------------------------------------------------
__global__ __launch_bounds__(256) void k_agg4(
    const float* __restrict__ src, const float* __restrict__ wlog,
    float* __restrict__ dst)
{
    int tid = blockIdx.x * 256 + threadIdx.x;        // span id, 36864 total
    int cb  = blockIdx.y;
    int n   = tid / (HW_ / 4);
    int r   = tid - n * (HW_ / 4);
    int hi  = r / (W_ / 4);
    int w4  = (r - hi * (W_ / 4)) * 4;

    int h0 = (hi == 0) ? 1 : hi - 1;
    int h2 = (hi == H_ - 1) ? H_ - 2 : hi + 1;
    int rows0 = h0 * W_, rows1 = hi * W_, rows2 = h2 * W_;

    int offL = (w4 == 0)   ? 1   : w4 - 1;
    int offR = (w4 == 380) ? 382 : w4 + 4;

    const float* wl = wlog + n * 9 * HW_ + rows1 + w4;
    float4 wv[9];
#pragma unroll
    for (int k = 0; k < 9; k++) wv[k] = *(const float4*)(wl + k * HW_);
    float4 m = wv[0];
#pragma unroll
    for (int k = 1; k < 9; k++) {
        m.x = fmaxf(m.x, wv[k].x); m.y = fmaxf(m.y, wv[k].y);
        m.z = fmaxf(m.z, wv[k].z); m.w = fmaxf(m.w, wv[k].w);
    }
    float4 sum = make_float4(0.f, 0.f, 0.f, 0.f);
#pragma unroll
    for (int k = 0; k < 9; k++) {
        wv[k].x = __expf(wv[k].x - m.x); sum.x += wv[k].x;
        wv[k].y = __expf(wv[k].y - m.y); sum.y += wv[k].y;
        wv[k].z = __expf(wv[k].z - m.z); sum.z += wv[k].z;
        wv[k].w = __expf(wv[k].w - m.w); sum.w += wv[k].w;
    }
    float4 inv = make_float4(1.f / sum.x, 1.f / sum.y, 1.f / sum.z, 1.f / sum.w);
#pragma unroll
    for (int k = 0; k < 9; k++) {
        wv[k].x *= inv.x; wv[k].y *= inv.y; wv[k].z *= inv.z; wv[k].w *= inv.w;
    }

    const float* srcn = src + n * (64 * HW_);
    float* dstn = dst + n * (64 * HW_) + rows1 + w4;

#pragma unroll
    for (int ci = 0; ci < 8; ci++) {
        int c = cb * 8 + ci;
        const float* sp = srcn + c * HW_;
        float4 acc = make_float4(0.f, 0.f, 0.f, 0.f);
        int rr[3] = {rows0, rows1, rows2};
#pragma unroll
        for (int krow = 0; krow < 3; krow++) {
            const float* rowp = sp + rr[krow];
            float4 cv = *(const float4*)(rowp + w4);
            float  lf = rowp[offL];
            float  rt = rowp[offR];
            float4 wL = wv[krow * 3 + 0];
            float4 wC = wv[krow * 3 + 1];
            float4 wR = wv[krow * 3 + 2];
            acc.x = fmaf(wL.x, lf,   acc.x);
            acc.y = fmaf(wL.y, cv.x, acc.y);
            acc.z = fmaf(wL.z, cv.y, acc.z);
            acc.w = fmaf(wL.w, cv.z, acc.w);
            acc.x = fmaf(wC.x, cv.x, acc.x);
            acc.y = fmaf(wC.y, cv.y, acc.y);
            acc.z = fmaf(wC.z, cv.z, acc.z);
            acc.w = fmaf(wC.w, cv.w, acc.w);
            acc.x = fmaf(wR.x, cv.y, acc.x);
            acc.y = fmaf(wR.y, cv.z, acc.y);
            acc.z = fmaf(wR.z, cv.w, acc.z);
            acc.w = fmaf(wR.w, rt,   acc.w);
        }
        *(float4*)(dstn + c * HW_) = acc;
    }
}

// ---------------------------------------------------------------------------
extern "C" void kernel_launch(void* const* d_in, const int* in_sizes, int n_in,
                              void* d_out, int out_size, void* d_ws, size_t ws_size,
                              hipStream_t stream)
{
    const float* x    = (const float*)d_in[0];
    const float* g    = (const float*)d_in[1];
    const float* w_q  = (const float*)d_in[2];
    const float* b_q  = (const float*)d_in[3];
    const float* w_k  = (const float*)d_in[4];
    const float* b_k  = (const float*)d_in[5];
    const float* w_v  = (const float*)d_in[6];
    const float* b_v  = (const float*)d_in[7];
    const float* w_g  = (const float*)d_in[8];
    const float* b_g  = (const float*)d_in[9];
    const float* w_p  = (const float*)d_in[10];
    // d_in[11] = b_p (cancels in center-minus-neighbor subtraction)
    const float* bn1g = (const float*)d_in[12];
    const float* bn1b = (const float*)d_in[13];
    const float* bn1m = (const float*)d_in[14];
    const float* bn1v = (const float*)d_in[15];
    const float* w1a  = (const float*)d_in[16];
    const float* bn2g = (const float*)d_in[17];
    const float* bn2b = (const float*)d_in[18];
    const float* bn2m = (const float*)d_in[19];
    const float* bn2v = (const float*)d_in[20];
    const float* w1b  = (const float*)d_in[21];
    const float* b1b  = (const float*)d_in[22];
    const float* bn3g = (const float*)d_in[23];
    const float* bn3b = (const float*)d_in[24];
    const float* bn3m = (const float*)d_in[25];
    const float* bn3v = (const float*)d_in[26];
    const float* w2a  = (const float*)d_in[27];
    const float* b2a  = (const float*)d_in[28];

    float* ws    = (float*)d_ws;
    float* x1    = ws;                     // [2][HW][16] px-major = 2359296 f
    float* x2    = x1 + 2359296;           // [2][HW][16] px-major
    float* gg    = x2 + 2359296;           // [2][HW][16] px-major
    float* out1  = gg + 2359296;           // [2][64][HW] ch-major = 9437184 f
    float* w1log = out1 + 9437184;         // [2][9][HW] = 1327104 f
    float* w2log = w1log + 1327104;        // 1327104 f
    float* prep  = w2log + 1327104;        // 100 f  (total ~76.7 MB)
    float* x3    = (float*)d_out;          // d_out doubles as x3 scratch

    k_prep<<<1, 128, 0, stream>>>(bn1g, bn1b, bn1m, bn1v,
                                  bn2g, bn2b, bn2m, bn2v,
                                  bn3g, bn3b, bn3m, bn3v, prep);

    k_projall<<<dim3(288, 4), 256, 0, stream>>>(x, g, w_q, b_q, w_k, b_k,
                                                w_v, b_v, w_g, b_g,
                                                x1, x2, x3, gg);

    WParams P;
    P.x1 = x1; P.x2 = x2; P.gg = gg;
    P.wp = w_p;
    P.w1a = w1a; P.w1b = w1b; P.b1b = b1b; P.w2a = w2a; P.b2a = b2a;
    P.prep = prep;
    P.w1o = w1log; P.w2o = w2log;
    k_wtap3<<<dim3(576, 3), 256, 0, stream>>>(P);

    k_agg4<<<dim3(144, 8), 256, 0, stream>>>(x3, w1log, out1);            // agg1
    k_agg4<<<dim3(144, 8), 256, 0, stream>>>(out1, w2log, (float*)d_out); // agg2
}

// Round 17
// 134.866 us; speedup vs baseline: 1.3178x; 1.3178x over previous
//
#include <hip/hip_runtime.h>
#include <math.h>

#define H_ 192
#define W_ 384
#define HW_ 73728

// ---------------------------------------------------------------------------
// K0: fold BN constants once.  prep layout (floats):
// [0..17] s1, [18..35] t1, [36..51] s2, [52..67] t2, [68..83] s3, [84..99] t3
// ---------------------------------------------------------------------------
__global__ void k_prep(
    const float* __restrict__ bn1g, const float* __restrict__ bn1b,
    const float* __restrict__ bn1m, const float* __restrict__ bn1v,
    const float* __restrict__ bn2g, const float* __restrict__ bn2b,
    const float* __restrict__ bn2m, const float* __restrict__ bn2v,
    const float* __restrict__ bn3g, const float* __restrict__ bn3b,
    const float* __restrict__ bn3m, const float* __restrict__ bn3v,
    float* __restrict__ prep)
{
    int t = threadIdx.x;
    if (t < 18) {
        float sc = bn1g[t] * rsqrtf(bn1v[t] + 1e-5f);
        prep[t] = sc; prep[18 + t] = bn1b[t] - bn1m[t] * sc;
    } else if (t >= 32 && t < 48) {
        int c = t - 32;
        float sc = bn2g[c] * rsqrtf(bn2v[c] + 1e-5f);
        prep[36 + c] = sc; prep[52 + c] = bn2b[c] - bn2m[c] * sc;
    } else if (t >= 64 && t < 80) {
        int c = t - 64;
        float sc = bn3g[c] * rsqrtf(bn3v[c] + 1e-5f);
        prep[68 + c] = sc; prep[84 + c] = bn3b[c] - bn3m[c] * sc;
    }
}

// ---------------------------------------------------------------------------
// K1: all projections in one dispatch. grid (288, 4), 2 px/thread (float2).
// blockIdx.y: 0 = q+k, 1 = v[0:32], 2 = v[32:64], 3 = gg (single pass).
// R8/R12-proven shape: batch-4 prefetch for qk/v, batch-8 for gg; VGPR ~44.
// Weights via uniform scalar loads (SGPR operands). All ch-major.
// ---------------------------------------------------------------------------
__global__ __launch_bounds__(256) void k_projall(
    const float* __restrict__ x, const float* __restrict__ g,
    const float* __restrict__ wq, const float* __restrict__ bq,
    const float* __restrict__ wk, const float* __restrict__ bk,
    const float* __restrict__ wv, const float* __restrict__ bv,
    const float* __restrict__ wg, const float* __restrict__ bg,
    float* __restrict__ x1, float* __restrict__ x2, float* __restrict__ x3,
    float* __restrict__ gg)
{
    int slab = blockIdx.y;
    int tid = blockIdx.x * 256 + threadIdx.x;   // 0..73727
    int n  = tid / (HW_ / 2);
    int s2 = (tid - n * (HW_ / 2)) * 2;

    if (slab == 0) {
        // ---- q + k (x read once for both) ----
        float2 aq[16], ak[16];
#pragma unroll
        for (int o = 0; o < 16; o++) {
            float b0 = bq[o], b1 = bk[o];
            aq[o] = make_float2(b0, b0); ak[o] = make_float2(b1, b1);
        }
        const float* xp = x + n * (64 * HW_) + s2;
#pragma unroll 1
        for (int c0 = 0; c0 < 64; c0 += 4) {
            float2 v[4];
#pragma unroll
            for (int j = 0; j < 4; j++) v[j] = *(const float2*)(xp + (c0 + j) * HW_);
#pragma unroll
            for (int j = 0; j < 4; j++) {
#pragma unroll
                for (int o = 0; o < 16; o++) {
                    float w0 = wq[o * 64 + c0 + j];
                    float w1 = wk[o * 64 + c0 + j];
                    aq[o].x = fmaf(w0, v[j].x, aq[o].x);
                    aq[o].y = fmaf(w0, v[j].y, aq[o].y);
                    ak[o].x = fmaf(w1, v[j].x, ak[o].x);
                    ak[o].y = fmaf(w1, v[j].y, ak[o].y);
                }
            }
        }
        float* d1 = x1 + n * (16 * HW_) + s2;
        float* d2 = x2 + n * (16 * HW_) + s2;
#pragma unroll
        for (int o = 0; o < 16; o++) {
            *(float2*)(d1 + o * HW_) = aq[o];
            *(float2*)(d2 + o * HW_) = ak[o];
        }
    } else if (slab <= 2) {
        // ---- v half (32 outputs) ----
        int q = slab - 1;
        const float* wsel = wv + q * 2048;
        const float* bsel = bv + q * 32;
        float2 av[32];
#pragma unroll
        for (int o = 0; o < 32; o++) { float b = bsel[o]; av[o] = make_float2(b, b); }
        const float* xp = x + n * (64 * HW_) + s2;
#pragma unroll 1
        for (int c0 = 0; c0 < 64; c0 += 4) {
            float2 v[4];
#pragma unroll
            for (int j = 0; j < 4; j++) v[j] = *(const float2*)(xp + (c0 + j) * HW_);
#pragma unroll
            for (int j = 0; j < 4; j++) {
#pragma unroll
                for (int o = 0; o < 32; o++) {
                    float w = wsel[o * 64 + c0 + j];
                    av[o].x = fmaf(w, v[j].x, av[o].x);
                    av[o].y = fmaf(w, v[j].y, av[o].y);
                }
            }
        }
        float* dst = x3 + (n * 64 + q * 32) * HW_ + s2;
#pragma unroll
        for (int o = 0; o < 32; o++) *(float2*)(dst + o * HW_) = av[o];
    } else {
        // ---- gg: all 16 outputs, single pass over g ----
        float2 a[16];
#pragma unroll
        for (int o = 0; o < 16; o++) { float b = bg[o]; a[o] = make_float2(b, b); }
        const float* gp = g + n * (128 * HW_) + s2;
#pragma unroll 1
        for (int c0 = 0; c0 < 128; c0 += 8) {
            float2 v[8];
#pragma unroll
            for (int j = 0; j < 8; j++) v[j] = *(const float2*)(gp + (c0 + j) * HW_);
#pragma unroll
            for (int j = 0; j < 8; j++) {
#pragma unroll
                for (int o = 0; o < 16; o++) {
                    float w = wg[o * 128 + c0 + j];
                    a[o].x = fmaf(w, v[j].x, a[o].x);
                    a[o].y = fmaf(w, v[j].y, a[o].y);
                }
            }
        }
        float* dst = gg + n * (16 * HW_) + s2;
#pragma unroll
        for (int o = 0; o < 16; o++) *(float2*)(dst + o * HW_) = a[o];
    }
}

// ---------------------------------------------------------------------------
// K2: tap-parallel weight logits, 1 px/thread, ZERO LDS, phase-batched loads.
// grid (576, 9). 32 independent loads issued before any use (phase A: x1/x2),
// then register-only MLP; phase B likewise for gg. BN from prep table.
// ---------------------------------------------------------------------------
struct WParams {
    const float *x1, *x2, *gg;
    const float *wp;
    const float *w1a, *w1b, *b1b, *w2a, *b2a;
    const float *prep;
    float *w1o, *w2o;   // [n][9][HW] raw logits
};

__global__ __launch_bounds__(256) void k_wtap_p(WParams P)
{
    const float* pr = P.prep;

    int k  = blockIdx.y;          // 0..8, uniform
    int ki = k / 3, kj = k - ki * 3;

    int p = blockIdx.x * 256 + threadIdx.x;
    int n = p / HW_, s = p - n * HW_;
    int hi = s / W_, wi = s - hi * W_;

    int hn = hi + ki - 1; hn = (hn < 0) ? -hn : ((hn >= H_) ? 2 * (H_ - 1) - hn : hn);
    int wn = wi + kj - 1; wn = (wn < 0) ? -wn : ((wn >= W_) ? 2 * (W_ - 1) - wn : wn);
    int snk = hn * W_ + wn;
    float dlh = (float)(hi - hn) * (2.0f / (H_ - 1));
    float dlw = (float)(wi - wn) * (2.0f / (W_ - 1));

    const float* x1p = P.x1 + n * (16 * HW_) + s;
    const float* x2p = P.x2 + n * (16 * HW_) + snk;
    const float* ggc = P.gg + n * (16 * HW_) + s;
    const float* ggn = P.gg + n * (16 * HW_) + snk;

    // ---- phase A: 32 independent loads ----
    float a0[16], a1[16];
#pragma unroll
    for (int c = 0; c < 16; c++) a0[c] = x1p[c * HW_];
#pragma unroll
    for (int c = 0; c < 16; c++) a1[c] = x2p[c * HW_];

    float f[16];
#pragma unroll
    for (int c = 0; c < 16; c++)
        f[c] = fmaxf(fmaf(a0[c] - a1[c], pr[c], pr[18 + c]), 0.0f);

    float h1[16];
#pragma unroll
    for (int o = 0; o < 16; o++) h1[o] = 0.0f;
#pragma unroll
    for (int c = 0; c < 16; c++) {
#pragma unroll
        for (int o = 0; o < 16; o++) h1[o] = fmaf(P.w1a[o * 18 + c], f[c], h1[o]);
    }
#pragma unroll
    for (int pc = 0; pc < 2; pc++) {
        float ff = fmaxf(fmaf(P.wp[pc * 2 + 0] * dlw + P.wp[pc * 2 + 1] * dlh,
                              pr[16 + pc], pr[34 + pc]), 0.0f);
#pragma unroll
        for (int o = 0; o < 16; o++) h1[o] = fmaf(P.w1a[o * 18 + 16 + pc], ff, h1[o]);
    }
    float l1 = P.b1b[0];
#pragma unroll
    for (int o = 0; o < 16; o++)
        l1 = fmaf(P.w1b[o], fmaxf(fmaf(h1[o], pr[36 + o], pr[52 + o]), 0.0f), l1);

    // ---- phase B: 32 independent loads ----
    float b0[16], b1v[16];
#pragma unroll
    for (int c = 0; c < 16; c++) b0[c] = ggc[c * HW_];
#pragma unroll
    for (int c = 0; c < 16; c++) b1v[c] = ggn[c * HW_];

    float l2 = P.b2a[0];
#pragma unroll
    for (int c = 0; c < 16; c++)
        l2 = fmaf(P.w2a[c], fmaxf(fmaf(b0[c] - b1v[c], pr[68 + c], pr[84 + c]), 0.0f), l2);

    P.w1o[(n * 9 + k) * HW_ + s] = l1;
    P.w2o[(n * 9 + k) * HW_ + s] = l2;
}

// ---------------------------------------------------------------------------
// K3: pixel-vectorized 9-tap aggregation + in-register softmax.
// grid (144, 8): 8-channel slabs.
// ---------------------------------------------------------------------------
__global__ __launch_bounds__(256) void k_agg4(
    const float* __restrict__ src, const float* __restrict__ wlog,
    float* __restrict__ dst)
{
    int tid = blockIdx.x * 256 + threadIdx.x;        // span id, 36864 total
    int cb  = blockIdx.y;
    int n   = tid / (HW_ / 4);
    int r   = tid - n * (HW_ / 4);
    int hi  = r / (W_ / 4);
    int w4  = (r - hi * (W_ / 4)) * 4;

    int h0 = (hi == 0) ? 1 : hi - 1;
    int h2 = (hi == H_ - 1) ? H_ - 2 : hi + 1;
    int rows0 = h0 * W_, rows1 = hi * W_, rows2 = h2 * W_;

    int offL = (w4 == 0)   ? 1   : w4 - 1;
    int offR = (w4 == 380) ? 382 : w4 + 4;

    const float* wl = wlog + n * 9 * HW_ + rows1 + w4;
    float4 wv[9];
#pragma unroll
    for (int k = 0; k < 9; k++) wv[k] = *(const float4*)(wl + k * HW_);
    float4 m = wv[0];
#pragma unroll
    for (int k = 1; k < 9; k++) {
        m.x = fmaxf(m.x, wv[k].x); m.y = fmaxf(m.y, wv[k].y);
        m.z = fmaxf(m.z, wv[k].z); m.w = fmaxf(m.w, wv[k].w);
    }
    float4 sum = make_float4(0.f, 0.f, 0.f, 0.f);
#pragma unroll
    for (int k = 0; k < 9; k++) {
        wv[k].x = __expf(wv[k].x - m.x); sum.x += wv[k].x;
        wv[k].y = __expf(wv[k].y - m.y); sum.y += wv[k].y;
        wv[k].z = __expf(wv[k].z - m.z); sum.z += wv[k].z;
        wv[k].w = __expf(wv[k].w - m.w); sum.w += wv[k].w;
    }
    float4 inv = make_float4(1.f / sum.x, 1.f / sum.y, 1.f / sum.z, 1.f / sum.w);
#pragma unroll
    for (int k = 0; k < 9; k++) {
        wv[k].x *= inv.x; wv[k].y *= inv.y; wv[k].z *= inv.z; wv[k].w *= inv.w;
    }

    const float* srcn = src + n * (64 * HW_);
    float* dstn = dst + n * (64 * HW_) + rows1 + w4;

#pragma unroll
    for (int ci = 0; ci < 8; ci++) {
        int c = cb * 8 + ci;
        const float* sp = srcn + c * HW_;
        float4 acc = make_float4(0.f, 0.f, 0.f, 0.f);
        int rr[3] = {rows0, rows1, rows2};
#pragma unroll
        for (int krow = 0; krow < 3; krow++) {
            const float* rowp = sp + rr[krow];
            float4 cv = *(const float4*)(rowp + w4);
            float  lf = rowp[offL];
            float  rt = rowp[offR];
            float4 wL = wv[krow * 3 + 0];
            float4 wC = wv[krow * 3 + 1];
            float4 wR = wv[krow * 3 + 2];
            acc.x = fmaf(wL.x, lf,   acc.x);
            acc.y = fmaf(wL.y, cv.x, acc.y);
            acc.z = fmaf(wL.z, cv.y, acc.z);
            acc.w = fmaf(wL.w, cv.z, acc.w);
            acc.x = fmaf(wC.x, cv.x, acc.x);
            acc.y = fmaf(wC.y, cv.y, acc.y);
            acc.z = fmaf(wC.z, cv.z, acc.z);
            acc.w = fmaf(wC.w, cv.w, acc.w);
            acc.x = fmaf(wR.x, cv.y, acc.x);
            acc.y = fmaf(wR.y, cv.z, acc.y);
            acc.z = fmaf(wR.z, cv.w, acc.z);
            acc.w = fmaf(wR.w, rt,   acc.w);
        }
        *(float4*)(dstn + c * HW_) = acc;
    }
}

// ---------------------------------------------------------------------------
extern "C" void kernel_launch(void* const* d_in, const int* in_sizes, int n_in,
                              void* d_out, int out_size, void* d_ws, size_t ws_size,
                              hipStream_t stream)
{
    const float* x    = (const float*)d_in[0];
    const float* g    = (const float*)d_in[1];
    const float* w_q  = (const float*)d_in[2];
    const float* b_q  = (const float*)d_in[3];
    const float* w_k  = (const float*)d_in[4];
    const float* b_k  = (const float*)d_in[5];
    const float* w_v  = (const float*)d_in[6];
    const float* b_v  = (const float*)d_in[7];
    const float* w_g  = (const float*)d_in[8];
    const float* b_g  = (const float*)d_in[9];
    const float* w_p  = (const float*)d_in[10];
    // d_in[11] = b_p (cancels in center-minus-neighbor subtraction)
    const float* bn1g = (const float*)d_in[12];
    const float* bn1b = (const float*)d_in[13];
    const float* bn1m = (const float*)d_in[14];
    const float* bn1v = (const float*)d_in[15];
    const float* w1a  = (const float*)d_in[16];
    const float* bn2g = (const float*)d_in[17];
    const float* bn2b = (const float*)d_in[18];
    const float* bn2m = (const float*)d_in[19];
    const float* bn2v = (const float*)d_in[20];
    const float* w1b  = (const float*)d_in[21];
    const float* b1b  = (const float*)d_in[22];
    const float* bn3g = (const float*)d_in[23];
    const float* bn3b = (const float*)d_in[24];
    const float* bn3m = (const float*)d_in[25];
    const float* bn3v = (const float*)d_in[26];
    const float* w2a  = (const float*)d_in[27];
    const float* b2a  = (const float*)d_in[28];

    float* ws    = (float*)d_ws;
    float* x1    = ws;                     // 2*16*HW = 2359296 f
    float* x2    = x1 + 2359296;           // 2359296 f
    float* gg    = x2 + 2359296;           // 2359296 f
    float* out1  = gg + 2359296;           // 2*64*HW = 9437184 f
    float* w1log = out1 + 9437184;         // 2*9*HW = 1327104 f
    float* w2log = w1log + 1327104;        // 1327104 f
    float* prep  = w2log + 1327104;        // 100 f  (total ~76.7 MB)
    float* x3    = (float*)d_out;          // d_out doubles as x3 scratch

    k_prep<<<1, 128, 0, stream>>>(bn1g, bn1b, bn1m, bn1v,
                                  bn2g, bn2b, bn2m, bn2v,
                                  bn3g, bn3b, bn3m, bn3v, prep);

    k_projall<<<dim3(288, 4), 256, 0, stream>>>(x, g, w_q, b_q, w_k, b_k,
                                                w_v, b_v, w_g, b_g,
                                                x1, x2, x3, gg);

    WParams P;
    P.x1 = x1; P.x2 = x2; P.gg = gg;
    P.wp = w_p;
    P.w1a = w1a; P.w1b = w1b; P.b1b = b1b; P.w2a = w2a; P.b2a = b2a;
    P.prep = prep;
    P.w1o = w1log; P.w2o = w2log;
    k_wtap_p<<<dim3(576, 9), 256, 0, stream>>>(P);

    k_agg4<<<dim3(144, 8), 256, 0, stream>>>(x3, w1log, out1);            // agg1
    k_agg4<<<dim3(144, 8), 256, 0, stream>>>(out1, w2log, (float*)d_out); // agg2
}

// Round 18
// 133.892 us; speedup vs baseline: 1.3274x; 1.0073x over previous
//
#include <hip/hip_runtime.h>
#include <math.h>

#define H_ 192
#define W_ 384
#define HW_ 73728

// ---------------------------------------------------------------------------
// K0: fold BN constants once.  prep layout (floats):
// [0..17] s1, [18..35] t1, [36..51] s2, [52..67] t2, [68..83] s3, [84..99] t3
// ---------------------------------------------------------------------------
__global__ void k_prep(
    const float* __restrict__ bn1g, const float* __restrict__ bn1b,
    const float* __restrict__ bn1m, const float* __restrict__ bn1v,
    const float* __restrict__ bn2g, const float* __restrict__ bn2b,
    const float* __restrict__ bn2m, const float* __restrict__ bn2v,
    const float* __restrict__ bn3g, const float* __restrict__ bn3b,
    const float* __restrict__ bn3m, const float* __restrict__ bn3v,
    float* __restrict__ prep)
{
    int t = threadIdx.x;
    if (t < 18) {
        float sc = bn1g[t] * rsqrtf(bn1v[t] + 1e-5f);
        prep[t] = sc; prep[18 + t] = bn1b[t] - bn1m[t] * sc;
    } else if (t >= 32 && t < 48) {
        int c = t - 32;
        float sc = bn2g[c] * rsqrtf(bn2v[c] + 1e-5f);
        prep[36 + c] = sc; prep[52 + c] = bn2b[c] - bn2m[c] * sc;
    } else if (t >= 64 && t < 80) {
        int c = t - 64;
        float sc = bn3g[c] * rsqrtf(bn3v[c] + 1e-5f);
        prep[68 + c] = sc; prep[84 + c] = bn3b[c] - bn3m[c] * sc;
    }
}

// ---------------------------------------------------------------------------
// K1: all projections, R12 shape + 1-deep software pipeline:
// load batch c0+4 BEFORE FMA-ing batch c0 (load latency hides under FMAs).
// grid (288, 4), 2 px/thread (float2). blockIdx.y: 0=q+k, 1=v[0:32],
// 2=v[32:64], 3=gg. Weights via uniform scalar loads. All ch-major.
// ---------------------------------------------------------------------------
__global__ __launch_bounds__(256) void k_projall(
    const float* __restrict__ x, const float* __restrict__ g,
    const float* __restrict__ wq, const float* __restrict__ bq,
    const float* __restrict__ wk, const float* __restrict__ bk,
    const float* __restrict__ wv, const float* __restrict__ bv,
    const float* __restrict__ wg, const float* __restrict__ bg,
    float* __restrict__ x1, float* __restrict__ x2, float* __restrict__ x3,
    float* __restrict__ gg)
{
    int slab = blockIdx.y;
    int tid = blockIdx.x * 256 + threadIdx.x;   // 0..73727
    int n  = tid / (HW_ / 2);
    int s2 = (tid - n * (HW_ / 2)) * 2;

    if (slab == 0) {
        // ---- q + k (x read once for both) ----
        float2 aq[16], ak[16];
#pragma unroll
        for (int o = 0; o < 16; o++) {
            float b0 = bq[o], b1 = bk[o];
            aq[o] = make_float2(b0, b0); ak[o] = make_float2(b1, b1);
        }
        const float* xp = x + n * (64 * HW_) + s2;
        float2 cur[4];
#pragma unroll
        for (int j = 0; j < 4; j++) cur[j] = *(const float2*)(xp + j * HW_);
#pragma unroll 1
        for (int c0 = 0; c0 < 60; c0 += 4) {
            float2 nxt[4];
#pragma unroll
            for (int j = 0; j < 4; j++) nxt[j] = *(const float2*)(xp + (c0 + 4 + j) * HW_);
#pragma unroll
            for (int j = 0; j < 4; j++) {
#pragma unroll
                for (int o = 0; o < 16; o++) {
                    float w0 = wq[o * 64 + c0 + j];
                    float w1 = wk[o * 64 + c0 + j];
                    aq[o].x = fmaf(w0, cur[j].x, aq[o].x);
                    aq[o].y = fmaf(w0, cur[j].y, aq[o].y);
                    ak[o].x = fmaf(w1, cur[j].x, ak[o].x);
                    ak[o].y = fmaf(w1, cur[j].y, ak[o].y);
                }
            }
#pragma unroll
            for (int j = 0; j < 4; j++) cur[j] = nxt[j];
        }
#pragma unroll
        for (int j = 0; j < 4; j++) {
#pragma unroll
            for (int o = 0; o < 16; o++) {
                float w0 = wq[o * 64 + 60 + j];
                float w1 = wk[o * 64 + 60 + j];
                aq[o].x = fmaf(w0, cur[j].x, aq[o].x);
                aq[o].y = fmaf(w0, cur[j].y, aq[o].y);
                ak[o].x = fmaf(w1, cur[j].x, ak[o].x);
                ak[o].y = fmaf(w1, cur[j].y, ak[o].y);
            }
        }
        float* d1 = x1 + n * (16 * HW_) + s2;
        float* d2 = x2 + n * (16 * HW_) + s2;
#pragma unroll
        for (int o = 0; o < 16; o++) {
            *(float2*)(d1 + o * HW_) = aq[o];
            *(float2*)(d2 + o * HW_) = ak[o];
        }
    } else if (slab <= 2) {
        // ---- v half (32 outputs) ----
        int q = slab - 1;
        const float* wsel = wv + q * 2048;
        const float* bsel = bv + q * 32;
        float2 av[32];
#pragma unroll
        for (int o = 0; o < 32; o++) { float b = bsel[o]; av[o] = make_float2(b, b); }
        const float* xp = x + n * (64 * HW_) + s2;
        float2 cur[4];
#pragma unroll
        for (int j = 0; j < 4; j++) cur[j] = *(const float2*)(xp + j * HW_);
#pragma unroll 1
        for (int c0 = 0; c0 < 60; c0 += 4) {
            float2 nxt[4];
#pragma unroll
            for (int j = 0; j < 4; j++) nxt[j] = *(const float2*)(xp + (c0 + 4 + j) * HW_);
#pragma unroll
            for (int j = 0; j < 4; j++) {
#pragma unroll
                for (int o = 0; o < 32; o++) {
                    float w = wsel[o * 64 + c0 + j];
                    av[o].x = fmaf(w, cur[j].x, av[o].x);
                    av[o].y = fmaf(w, cur[j].y, av[o].y);
                }
            }
#pragma unroll
            for (int j = 0; j < 4; j++) cur[j] = nxt[j];
        }
#pragma unroll
        for (int j = 0; j < 4; j++) {
#pragma unroll
            for (int o = 0; o < 32; o++) {
                float w = wsel[o * 64 + 60 + j];
                av[o].x = fmaf(w, cur[j].x, av[o].x);
                av[o].y = fmaf(w, cur[j].y, av[o].y);
            }
        }
        float* dst = x3 + (n * 64 + q * 32) * HW_ + s2;
#pragma unroll
        for (int o = 0; o < 32; o++) *(float2*)(dst + o * HW_) = av[o];
    } else {
        // ---- gg: all 16 outputs, single pass over g ----
        float2 a[16];
#pragma unroll
        for (int o = 0; o < 16; o++) { float b = bg[o]; a[o] = make_float2(b, b); }
        const float* gp = g + n * (128 * HW_) + s2;
        float2 cur[8];
#pragma unroll
        for (int j = 0; j < 8; j++) cur[j] = *(const float2*)(gp + j * HW_);
#pragma unroll 1
        for (int c0 = 0; c0 < 120; c0 += 8) {
            float2 nxt[8];
#pragma unroll
            for (int j = 0; j < 8; j++) nxt[j] = *(const float2*)(gp + (c0 + 8 + j) * HW_);
#pragma unroll
            for (int j = 0; j < 8; j++) {
#pragma unroll
                for (int o = 0; o < 16; o++) {
                    float w = wg[o * 128 + c0 + j];
                    a[o].x = fmaf(w, cur[j].x, a[o].x);
                    a[o].y = fmaf(w, cur[j].y, a[o].y);
                }
            }
#pragma unroll
            for (int j = 0; j < 8; j++) cur[j] = nxt[j];
        }
#pragma unroll
        for (int j = 0; j < 8; j++) {
#pragma unroll
            for (int o = 0; o < 16; o++) {
                float w = wg[o * 128 + 120 + j];
                a[o].x = fmaf(w, cur[j].x, a[o].x);
                a[o].y = fmaf(w, cur[j].y, a[o].y);
            }
        }
        float* dst = gg + n * (16 * HW_) + s2;
#pragma unroll
        for (int o = 0; o < 16; o++) *(float2*)(dst + o * HW_) = a[o];
    }
}

// ---------------------------------------------------------------------------
// K2: tap-parallel weight logits, 1 px/thread, ZERO LDS, phase-batched loads.
// grid (576, 9). 32 independent loads issued before any use (phase A: x1/x2),
// then register-only MLP; phase B likewise for gg. BN from prep table.
// ---------------------------------------------------------------------------
struct WParams {
    const float *x1, *x2, *gg;
    const float *wp;
    const float *w1a, *w1b, *b1b, *w2a, *b2a;
    const float *prep;
    float *w1o, *w2o;   // [n][9][HW] raw logits
};

__global__ __launch_bounds__(256) void k_wtap_p(WParams P)
{
    const float* pr = P.prep;

    int k  = blockIdx.y;          // 0..8, uniform
    int ki = k / 3, kj = k - ki * 3;

    int p = blockIdx.x * 256 + threadIdx.x;
    int n = p / HW_, s = p - n * HW_;
    int hi = s / W_, wi = s - hi * W_;

    int hn = hi + ki - 1; hn = (hn < 0) ? -hn : ((hn >= H_) ? 2 * (H_ - 1) - hn : hn);
    int wn = wi + kj - 1; wn = (wn < 0) ? -wn : ((wn >= W_) ? 2 * (W_ - 1) - wn : wn);
    int snk = hn * W_ + wn;
    float dlh = (float)(hi - hn) * (2.0f / (H_ - 1));
    float dlw = (float)(wi - wn) * (2.0f / (W_ - 1));

    const float* x1p = P.x1 + n * (16 * HW_) + s;
    const float* x2p = P.x2 + n * (16 * HW_) + snk;
    const float* ggc = P.gg + n * (16 * HW_) + s;
    const float* ggn = P.gg + n * (16 * HW_) + snk;

    // ---- phase A: 32 independent loads ----
    float a0[16], a1[16];
#pragma unroll
    for (int c = 0; c < 16; c++) a0[c] = x1p[c * HW_];
#pragma unroll
    for (int c = 0; c < 16; c++) a1[c] = x2p[c * HW_];

    float f[16];
#pragma unroll
    for (int c = 0; c < 16; c++)
        f[c] = fmaxf(fmaf(a0[c] - a1[c], pr[c], pr[18 + c]), 0.0f);

    float h1[16];
#pragma unroll
    for (int o = 0; o < 16; o++) h1[o] = 0.0f;
#pragma unroll
    for (int c = 0; c < 16; c++) {
#pragma unroll
        for (int o = 0; o < 16; o++) h1[o] = fmaf(P.w1a[o * 18 + c], f[c], h1[o]);
    }
#pragma unroll
    for (int pc = 0; pc < 2; pc++) {
        float ff = fmaxf(fmaf(P.wp[pc * 2 + 0] * dlw + P.wp[pc * 2 + 1] * dlh,
                              pr[16 + pc], pr[34 + pc]), 0.0f);
#pragma unroll
        for (int o = 0; o < 16; o++) h1[o] = fmaf(P.w1a[o * 18 + 16 + pc], ff, h1[o]);
    }
    float l1 = P.b1b[0];
#pragma unroll
    for (int o = 0; o < 16; o++)
        l1 = fmaf(P.w1b[o], fmaxf(fmaf(h1[o], pr[36 + o], pr[52 + o]), 0.0f), l1);

    // ---- phase B: 32 independent loads ----
    float b0[16], b1v[16];
#pragma unroll
    for (int c = 0; c < 16; c++) b0[c] = ggc[c * HW_];
#pragma unroll
    for (int c = 0; c < 16; c++) b1v[c] = ggn[c * HW_];

    float l2 = P.b2a[0];
#pragma unroll
    for (int c = 0; c < 16; c++)
        l2 = fmaf(P.w2a[c], fmaxf(fmaf(b0[c] - b1v[c], pr[68 + c], pr[84 + c]), 0.0f), l2);

    P.w1o[(n * 9 + k) * HW_ + s] = l1;
    P.w2o[(n * 9 + k) * HW_ + s] = l2;
}

// ---------------------------------------------------------------------------
// K3: pixel-vectorized 9-tap aggregation + in-register softmax.
// grid (144, 8): 8-channel slabs.
// ---------------------------------------------------------------------------
__global__ __launch_bounds__(256) void k_agg4(
    const float* __restrict__ src, const float* __restrict__ wlog,
    float* __restrict__ dst)
{
    int tid = blockIdx.x * 256 + threadIdx.x;        // span id, 36864 total
    int cb  = blockIdx.y;
    int n   = tid / (HW_ / 4);
    int r   = tid - n * (HW_ / 4);
    int hi  = r / (W_ / 4);
    int w4  = (r - hi * (W_ / 4)) * 4;

    int h0 = (hi == 0) ? 1 : hi - 1;
    int h2 = (hi == H_ - 1) ? H_ - 2 : hi + 1;
    int rows0 = h0 * W_, rows1 = hi * W_, rows2 = h2 * W_;

    int offL = (w4 == 0)   ? 1   : w4 - 1;
    int offR = (w4 == 380) ? 382 : w4 + 4;

    const float* wl = wlog + n * 9 * HW_ + rows1 + w4;
    float4 wv[9];
#pragma unroll
    for (int k = 0; k < 9; k++) wv[k] = *(const float4*)(wl + k * HW_);
    float4 m = wv[0];
#pragma unroll
    for (int k = 1; k < 9; k++) {
        m.x = fmaxf(m.x, wv[k].x); m.y = fmaxf(m.y, wv[k].y);
        m.z = fmaxf(m.z, wv[k].z); m.w = fmaxf(m.w, wv[k].w);
    }
    float4 sum = make_float4(0.f, 0.f, 0.f, 0.f);
#pragma unroll
    for (int k = 0; k < 9; k++) {
        wv[k].x = __expf(wv[k].x - m.x); sum.x += wv[k].x;
        wv[k].y = __expf(wv[k].y - m.y); sum.y += wv[k].y;
        wv[k].z = __expf(wv[k].z - m.z); sum.z += wv[k].z;
        wv[k].w = __expf(wv[k].w - m.w); sum.w += wv[k].w;
    }
    float4 inv = make_float4(1.f / sum.x, 1.f / sum.y, 1.f / sum.z, 1.f / sum.w);
#pragma unroll
    for (int k = 0; k < 9; k++) {
        wv[k].x *= inv.x; wv[k].y *= inv.y; wv[k].z *= inv.z; wv[k].w *= inv.w;
    }

    const float* srcn = src + n * (64 * HW_);
    float* dstn = dst + n * (64 * HW_) + rows1 + w4;

#pragma unroll
    for (int ci = 0; ci < 8; ci++) {
        int c = cb * 8 + ci;
        const float* sp = srcn + c * HW_;
        float4 acc = make_float4(0.f, 0.f, 0.f, 0.f);
        int rr[3] = {rows0, rows1, rows2};
#pragma unroll
        for (int krow = 0; krow < 3; krow++) {
            const float* rowp = sp + rr[krow];
            float4 cv = *(const float4*)(rowp + w4);
            float  lf = rowp[offL];
            float  rt = rowp[offR];
            float4 wL = wv[krow * 3 + 0];
            float4 wC = wv[krow * 3 + 1];
            float4 wR = wv[krow * 3 + 2];
            acc.x = fmaf(wL.x, lf,   acc.x);
            acc.y = fmaf(wL.y, cv.x, acc.y);
            acc.z = fmaf(wL.z, cv.y, acc.z);
            acc.w = fmaf(wL.w, cv.z, acc.w);
            acc.x = fmaf(wC.x, cv.x, acc.x);
            acc.y = fmaf(wC.y, cv.y, acc.y);
            acc.z = fmaf(wC.z, cv.z, acc.z);
            acc.w = fmaf(wC.w, cv.w, acc.w);
            acc.x = fmaf(wR.x, cv.y, acc.x);
            acc.y = fmaf(wR.y, cv.z, acc.y);
            acc.z = fmaf(wR.z, cv.w, acc.z);
            acc.w = fmaf(wR.w, rt,   acc.w);
        }
        *(float4*)(dstn + c * HW_) = acc;
    }
}

// ---------------------------------------------------------------------------
extern "C" void kernel_launch(void* const* d_in, const int* in_sizes, int n_in,
                              void* d_out, int out_size, void* d_ws, size_t ws_size,
                              hipStream_t stream)
{
    const float* x    = (const float*)d_in[0];
    const float* g    = (const float*)d_in[1];
    const float* w_q  = (const float*)d_in[2];
    const float* b_q  = (const float*)d_in[3];
    const float* w_k  = (const float*)d_in[4];
    const float* b_k  = (const float*)d_in[5];
    const float* w_v  = (const float*)d_in[6];
    const float* b_v  = (const float*)d_in[7];
    const float* w_g  = (const float*)d_in[8];
    const float* b_g  = (const float*)d_in[9];
    const float* w_p  = (const float*)d_in[10];
    // d_in[11] = b_p (cancels in center-minus-neighbor subtraction)
    const float* bn1g = (const float*)d_in[12];
    const float* bn1b = (const float*)d_in[13];
    const float* bn1m = (const float*)d_in[14];
    const float* bn1v = (const float*)d_in[15];
    const float* w1a  = (const float*)d_in[16];
    const float* bn2g = (const float*)d_in[17];
    const float* bn2b = (const float*)d_in[18];
    const float* bn2m = (const float*)d_in[19];
    const float* bn2v = (const float*)d_in[20];
    const float* w1b  = (const float*)d_in[21];
    const float* b1b  = (const float*)d_in[22];
    const float* bn3g = (const float*)d_in[23];
    const float* bn3b = (const float*)d_in[24];
    const float* bn3m = (const float*)d_in[25];
    const float* bn3v = (const float*)d_in[26];
    const float* w2a  = (const float*)d_in[27];
    const float* b2a  = (const float*)d_in[28];

    float* ws    = (float*)d_ws;
    float* x1    = ws;                     // 2*16*HW = 2359296 f
    float* x2    = x1 + 2359296;           // 2359296 f
    float* gg    = x2 + 2359296;           // 2359296 f
    float* out1  = gg + 2359296;           // 2*64*HW = 9437184 f
    float* w1log = out1 + 9437184;         // 2*9*HW = 1327104 f
    float* w2log = w1log + 1327104;        // 1327104 f
    float* prep  = w2log + 1327104;        // 100 f  (total ~76.7 MB)
    float* x3    = (float*)d_out;          // d_out doubles as x3 scratch

    k_prep<<<1, 128, 0, stream>>>(bn1g, bn1b, bn1m, bn1v,
                                  bn2g, bn2b, bn2m, bn2v,
                                  bn3g, bn3b, bn3m, bn3v, prep);

    k_projall<<<dim3(288, 4), 256, 0, stream>>>(x, g, w_q, b_q, w_k, b_k,
                                                w_v, b_v, w_g, b_g,
                                                x1, x2, x3, gg);

    WParams P;
    P.x1 = x1; P.x2 = x2; P.gg = gg;
    P.wp = w_p;
    P.w1a = w1a; P.w1b = w1b; P.b1b = b1b; P.w2a = w2a; P.b2a = b2a;
    P.prep = prep;
    P.w1o = w1log; P.w2o = w2log;
    k_wtap_p<<<dim3(576, 9), 256, 0, stream>>>(P);

    k_agg4<<<dim3(144, 8), 256, 0, stream>>>(x3, w1log, out1);            // agg1
    k_agg4<<<dim3(144, 8), 256, 0, stream>>>(out1, w2log, (float*)d_out); // agg2
}